// Round 12
// baseline (2338.728 us; speedup 1.0000x reference)
//
#include <hip/hip_runtime.h>

#define DEVINL static __device__ __forceinline__
// A wave's DS ops execute in issue order, so same-wave WAR/RAW through LDS
// needs only a compiler reorder fence (validated rounds 10-11).
#define CFENCE() asm volatile("" ::: "memory")

typedef float v2f __attribute__((ext_vector_type(2)));

DEVINL v2f mk2(float a, float b) { v2f r; r.x = a; r.y = b; return r; }
DEVINL v2f pkfma(v2f a, v2f b, v2f c) { return __builtin_elementwise_fma(a, b, c); }

constexpr float KE = 2.885390081777927f;   // 2*log2(e)

#if __has_builtin(__builtin_amdgcn_exp2f)
DEVINL float exp2_fast(float x) { return __builtin_amdgcn_exp2f(x); }
#else
DEVINL float exp2_fast(float x) { return __expf(x * 0.6931471805599453f); }
#endif

// tanh(x) with t = x*2*log2(e) pre-folded into weights: 1 - 2/(2^t+1).
DEVINL float tanh_pre(float t) {
  float e = exp2_fast(t);
  return 1.0f - 2.0f * __builtin_amdgcn_rcpf(e + 1.0f);
}

template <int CTRL>
DEVINL float dpp_add(float v) {
  int t = __builtin_amdgcn_update_dpp(0, __float_as_int(v), CTRL, 0xF, 0xF, true);
  return v + __int_as_float(t);
}
// After this, every lane of a 16-lane row holds its row's sum.
DEVINL float rowsum16(float v) {
  v = dpp_add<0xB1>(v);    // quad_perm [1,0,3,2]
  v = dpp_add<0x4E>(v);    // quad_perm [2,3,0,1]
  v = dpp_add<0x141>(v);   // row_half_mirror
  v = dpp_add<0x140>(v);   // row_mirror
  return v;
}
// Half-wave totals: lane31 = sum(lanes 0..31), lane63 = sum(lanes 32..63).
DEVINL float halves_total(float v) {
  v = rowsum16(v);
  v = dpp_add<0x142>(v);   // row_bcast15: row1 += lane15, row3 += lane47
  return v;
}
DEVINL float rlane(float v, int l) {
  return __int_as_float(__builtin_amdgcn_readlane(__float_as_int(v), l));
}

// 32-wide dot vs an LDS row (uniform address per half), packed fp32.
DEVINL float dot32(const float* hrow, const v2f* W, float bias) {
  const float4* hp = (const float4*)hrow;
  v2f a0 = mk2(bias, 0.f), a1 = mk2(0.f, 0.f);
  v2f a2 = mk2(0.f, 0.f), a3 = mk2(0.f, 0.f);
#pragma unroll
  for (int q = 0; q < 8; q += 2) {
    float4 x = hp[q], y = hp[q + 1];
    a0 = pkfma(mk2(x.x, x.y), W[2 * q + 0], a0);
    a1 = pkfma(mk2(x.z, x.w), W[2 * q + 1], a1);
    a2 = pkfma(mk2(y.x, y.y), W[2 * q + 2], a2);
    a3 = pkfma(mk2(y.z, y.w), W[2 * q + 3], a3);
  }
  v2f s = (a0 + a1) + (a2 + a3);
  return s.x + s.y;
}
// 16-wide partial dot (k-split r3 layer 1), packed fp32.
DEVINL float pdot16(const float* hrow, const v2f* W) {
  const float4* hp = (const float4*)hrow;
  v2f a0 = mk2(0.f, 0.f), a1 = mk2(0.f, 0.f);
  float4 x = hp[0], y = hp[1];
  a0 = pkfma(mk2(x.x, x.y), W[0], a0);
  a1 = pkfma(mk2(x.z, x.w), W[1], a1);
  a0 = pkfma(mk2(y.x, y.y), W[2], a0);
  a1 = pkfma(mk2(y.z, y.w), W[3], a1);
  x = hp[2]; y = hp[3];
  a0 = pkfma(mk2(x.x, x.y), W[4], a0);
  a1 = pkfma(mk2(x.z, x.w), W[5], a1);
  a0 = pkfma(mk2(y.x, y.y), W[6], a0);
  a1 = pkfma(mk2(y.z, y.w), W[7], a1);
  v2f s = a0 + a1;
  return s.x + s.y;
}

// wave = 1 batch element; lanes 0-31 = net r1 duties, lanes 32-63 = net r2.
// grid 4096 -> 16 waves/CU = 4 waves/EU.
__global__ __attribute__((amdgpu_flat_work_group_size(64, 64)))
__attribute__((amdgpu_waves_per_eu(4, 4))) void reac_kernel(
    const float* __restrict__ useq,   // [B][T] f32
    const float* __restrict__ xz0,    // [B][26] f32
    const float* __restrict__ r1W0, const float* __restrict__ r1b0,
    const float* __restrict__ r1W1, const float* __restrict__ r1b1,
    const float* __restrict__ r1W2, const float* __restrict__ r1b2,
    const float* __restrict__ r2W0, const float* __restrict__ r2b0,
    const float* __restrict__ r2W1, const float* __restrict__ r2b1,
    const float* __restrict__ r2W2, const float* __restrict__ r2b2,
    const float* __restrict__ r3W0, const float* __restrict__ r3b0,
    const float* __restrict__ r3W1, const float* __restrict__ r3b1,
    const float* __restrict__ r3W2, const float* __restrict__ r3b2,
    float2* __restrict__ out)         // [B][T] -> (x0,x1) f32
{
  const int lane = threadIdx.x;
  const int j = lane & 31;
  const bool hi = lane >= 32;      // high half = r2 net / z4 duties
  const int b = blockIdx.x;
  const int xaddr = ((lane ^ 32) << 2);   // ds_bpermute partner address

  auto xchg = [&](float v) -> float {
    return __int_as_float(__builtin_amdgcn_ds_bpermute(xaddr, __float_as_int(v)));
  };

  // ---- per-half net weights (column j), tanh prescale KE folded in ----
  const float* W0p = hi ? r2W0 : r1W0;
  const float* B0p = hi ? r2b0 : r1b0;
  const float* W1p = hi ? r2W1 : r1W1;
  const float* B1p = hi ? r2b1 : r1b1;
  const float* W2p = hi ? r2W2 : r1W2;
  const float sc = hi ? 0.2f : 0.3f;
  float w0K = W0p[j] * KE, b0K = B0p[j] * KE;
  float b1K = B1p[j] * KE;
  float w2sc = W2p[j] * sc;

  v2f W1v[16];
#pragma unroll
  for (int k = 0; k < 16; ++k)
    W1v[k] = mk2(W1p[(2 * k) * 32 + j] * KE, W1p[(2 * k + 1) * 32 + j] * KE);

  float W0C[24];
#pragma unroll
  for (int m = 0; m < 24; ++m) W0C[m] = r3W0[m * 32 + j] * KE;
  const int kbase = hi ? 16 : 0;
  v2f W1Cv[8];
#pragma unroll
  for (int k = 0; k < 8; ++k)
    W1Cv[k] = mk2(r3W1[(kbase + 2 * k) * 32 + j] * KE,
                  r3W1[(kbase + 2 * k + 1) * 32 + j] * KE);
  float b0CK = r3b0[j] * KE, b1CK = r3b1[j] * KE;
  float w2C02 = r3W2[j] * 0.2f;

  // wave-uniform scalars (biases folded with output scales)
  const float b2sA = r1b2[0] * 0.3f;
  const float b2sB = r2b2[0] * 0.2f;
  const float b2Cs = r3b2[0] * 0.2f - 0.05f;   // folds -F/V*0.5 of dCb

  __shared__ __align__(16) float h12[2][32];  // [net][neuron]
  __shared__ __align__(16) float hR3[3][32];  // [eval: z,z23,z4][neuron]

  // ---- z state in registers (wave-uniform), circular with period 8 ----
  float x0 = xz0[b * 26 + 0];
  float x1 = xz0[b * 26 + 1];
  float xp[16], up[8];
#pragma unroll
  for (int i = 0; i < 16; ++i) xp[i] = xz0[b * 26 + 2 + i];
#pragma unroll
  for (int i = 0; i < 8; ++i) up[i] = xz0[b * 26 + 18 + i];

  // RK stage: low half evaluates r1(sx), high half r2(sy); readlane both.
  auto stage = [&](float sxv, float syv, float rc_m05, float CafF,
                   float& kx, float& ky) {
    float sv = hi ? syv : sxv;
    float h = tanh_pre(fmaf(sv, w0K, b0K));
    CFENCE();                      // order write after previous readers
    h12[hi][j] = h;
    CFENCE();                      // order reads after the write
    float a = dot32(&h12[hi][0], W1v, b1K);
    float v = halves_total(tanh_pre(a) * w2sc);
    float ra = rlane(v, 31) + b2sA;       // r1 (uniform)
    float rb = rlane(v, 63) + b2sB;       // r2 (uniform)
    float dCa = fmaf(-0.03f, sxv, CafF) - ra;
    float dCb = fmaf(-0.02f, syv, fmaf(-3.0f, rb, ra) + rc_m05);
    kx = dCa * (1.0f / 0.3f);
    ky = dCb * (1.0f / 0.2f);
  };

  for (int tb = 0; tb < 32; ++tb) {
#pragma unroll
    for (int p = 0; p < 8; ++p) {
      const int t = tb * 8 + p;
      float u = useq[b * 256 + t];
      float CafF = fmaf(u, 0.05f, 0.05f);

      if (lane == 0) out[b * 256 + t] = make_float2(x0, x1);

      // ---- r3 layer 0 from registers: low = A(z), high = A(z4) ----
      float A = b0CK;
#pragma unroll
      for (int i = 0; i < 14; ++i) {
        float m = hi ? xp[(2 * p + 2 + i) & 15] : xp[(2 * p + i) & 15];
        A = fmaf(m, W0C[i], A);
      }
      {
        float m = hi ? x0 : xp[(2 * p + 14) & 15];
        A = fmaf(m, W0C[14], A);
        m = hi ? x1 : xp[(2 * p + 15) & 15];
        A = fmaf(m, W0C[15], A);
      }
#pragma unroll
      for (int i = 0; i < 8; ++i) A = fmaf(up[(p + i) & 7], W0C[16 + i], A);

      float Ap = xchg(A);                    // partner's A
      float tA = tanh_pre(A);
      CFENCE();
      hR3[hi ? 2 : 0][j] = tA;               // h(z) / h(z4)
      if (!hi) hR3[1][j] = tanh_pre(0.5f * (A + Ap));  // h(z23), exact
      CFENCE();
      float p0 = pdot16(&hR3[0][kbase], W1Cv);
      float p1 = pdot16(&hR3[1][kbase], W1Cv);
      float p2 = pdot16(&hR3[2][kbase], W1Cv);
      float o0 = p0 + xchg(p0) + b1CK;       // same value in both halves
      float o1 = p1 + xchg(p1) + b1CK;
      float o2 = p2 + xchg(p2) + b1CK;
      float v0 = halves_total(tanh_pre(o0) * w2C02);
      float v1 = halves_total(tanh_pre(o1) * w2C02);
      float v2 = halves_total(tanh_pre(o2) * w2C02);
      float rc1  = rlane(v0, 31) + b2Cs;     // = rc - 0.05 (uniform)
      float rc23 = rlane(v1, 31) + b2Cs;
      float rc4  = rlane(v2, 31) + b2Cs;

      // ---- RK stages ----
      float kx1, ky1, kx2, ky2, kx3, ky3, kx4, ky4;
      stage(x0, x1, rc1, CafF, kx1, ky1);
      stage(fmaf(kx1, 0.5f, x0), fmaf(ky1, 0.5f, x1), rc23, CafF, kx2, ky2);
      stage(fmaf(kx2, 0.5f, x0), fmaf(ky2, 0.5f, x1), rc23, CafF, kx3, ky3);
      stage(x0 + kx3, x1 + ky3, rc4, CafF, kx4, ky4);

      // ---- state update (registers; indices rotate by unroll) ----
      xp[(2 * p) & 15] = x0;       // slots rotating out receive current x
      xp[(2 * p + 1) & 15] = x1;
      up[p & 7] = u;               // oldest upseq slot receives u
      x0 += (kx1 + 2.0f * (kx2 + kx3) + kx4) * (1.0f / 6.0f);
      x1 += (ky1 + 2.0f * (ky2 + ky3) + ky4) * (1.0f / 6.0f);
    }
  }
}

extern "C" void kernel_launch(void* const* d_in, const int* in_sizes, int n_in,
                              void* d_out, int out_size, void* d_ws, size_t ws_size,
                              hipStream_t stream) {
  const float* p[20];
  for (int i = 0; i < 20; ++i) p[i] = (const float*)d_in[i];
  reac_kernel<<<dim3(4096), dim3(64), 0, stream>>>(
      p[0], p[1], p[2], p[3], p[4], p[5], p[6], p[7], p[8], p[9], p[10],
      p[11], p[12], p[13], p[14], p[15], p[16], p[17], p[18], p[19],
      (float2*)d_out);
}

// Round 15
// 851.821 us; speedup vs baseline: 2.7456x; 2.7456x over previous
//
#include <hip/hip_runtime.h>

#define DEVINL static __device__ __forceinline__
// Same-wave LDS ordering: compiler reorder fence only (validated r10/r12).
#define CFENCE() asm volatile("" ::: "memory")

typedef float v2f __attribute__((ext_vector_type(2)));

DEVINL v2f mk2(float a, float b) { v2f r; r.x = a; r.y = b; return r; }
DEVINL v2f pkfma(v2f a, v2f b, v2f c) { return __builtin_elementwise_fma(a, b, c); }

constexpr float KE = 2.885390081777927f;   // 2*log2(e)

#if __has_builtin(__builtin_amdgcn_exp2f)
DEVINL float exp2_fast(float x) { return __builtin_amdgcn_exp2f(x); }
#else
DEVINL float exp2_fast(float x) { return __expf(x * 0.6931471805599453f); }
#endif

// tanh(x) with t = x*2*log2(e) pre-folded into weights: 1 - 2/(2^t+1).
DEVINL float tanh_pre(float t) {
  float e = exp2_fast(t);
  return 1.0f - 2.0f * __builtin_amdgcn_rcpf(e + 1.0f);
}

template <int CTRL>
DEVINL float dpp_add(float v) {
  int t = __builtin_amdgcn_update_dpp(0, __float_as_int(v), CTRL, 0xF, 0xF, true);
  return v + __int_as_float(t);
}
// All-DPP half-wave totals: lane31 = sum(lanes 0..31), lane63 = sum(32..63).
// (Validated in r12 — replaces ds_swizzle xor16 tails and bpermute pairs.)
DEVINL float halves_total(float v) {
  v = dpp_add<0xB1>(v);    // quad_perm [1,0,3,2]
  v = dpp_add<0x4E>(v);    // quad_perm [2,3,0,1]
  v = dpp_add<0x141>(v);   // row_half_mirror
  v = dpp_add<0x140>(v);   // row_mirror
  v = dpp_add<0x142>(v);   // row_bcast15 -> lanes 31,63 hold half totals
  return v;
}
DEVINL float rlane(float v, int l) {
  return __int_as_float(__builtin_amdgcn_readlane(__float_as_int(v), l));
}

// 32-wide dot vs an LDS row (uniform address per half), packed fp32.
DEVINL float dot32(const float* hrow, const v2f* W, float bias) {
  const float4* hp = (const float4*)hrow;
  v2f a0 = mk2(bias, 0.f), a1 = mk2(0.f, 0.f);
  v2f a2 = mk2(0.f, 0.f), a3 = mk2(0.f, 0.f);
#pragma unroll
  for (int q = 0; q < 8; q += 2) {
    float4 x = hp[q], y = hp[q + 1];
    a0 = pkfma(mk2(x.x, x.y), W[2 * q + 0], a0);
    a1 = pkfma(mk2(x.z, x.w), W[2 * q + 1], a1);
    a2 = pkfma(mk2(y.x, y.y), W[2 * q + 2], a2);
    a3 = pkfma(mk2(y.z, y.w), W[2 * q + 3], a3);
  }
  v2f s = (a0 + a1) + (a2 + a3);
  return s.x + s.y;
}
// 16-wide partial dot (k-split r3 layer 1), packed fp32.
DEVINL float pdot16(const float* hrow, const v2f* W) {
  const float4* hp = (const float4*)hrow;
  v2f a0 = mk2(0.f, 0.f), a1 = mk2(0.f, 0.f);
  float4 x = hp[0], y = hp[1];
  a0 = pkfma(mk2(x.x, x.y), W[0], a0);
  a1 = pkfma(mk2(x.z, x.w), W[1], a1);
  a0 = pkfma(mk2(y.x, y.y), W[2], a0);
  a1 = pkfma(mk2(y.z, y.w), W[3], a1);
  x = hp[2]; y = hp[3];
  a0 = pkfma(mk2(x.x, x.y), W[4], a0);
  a1 = pkfma(mk2(x.z, x.w), W[5], a1);
  a0 = pkfma(mk2(y.x, y.y), W[6], a0);
  a1 = pkfma(mk2(y.z, y.w), W[7], a1);
  v2f s = a0 + a1;
  return s.x + s.y;
}

constexpr int TT = 256;

// wave = 1 batch element; lanes 0-31 = net r1 duties, lanes 32-63 = net r2.
// grid 4096 -> 16 waves/CU = 4 waves/EU.
__global__ __attribute__((amdgpu_flat_work_group_size(64, 64)))
__attribute__((amdgpu_waves_per_eu(4, 4))) void reac_kernel(
    const float* __restrict__ useq,   // [B][T] f32
    const float* __restrict__ xz0,    // [B][26] f32
    const float* __restrict__ r1W0, const float* __restrict__ r1b0,
    const float* __restrict__ r1W1, const float* __restrict__ r1b1,
    const float* __restrict__ r1W2, const float* __restrict__ r1b2,
    const float* __restrict__ r2W0, const float* __restrict__ r2b0,
    const float* __restrict__ r2W1, const float* __restrict__ r2b1,
    const float* __restrict__ r2W2, const float* __restrict__ r2b2,
    const float* __restrict__ r3W0, const float* __restrict__ r3b0,
    const float* __restrict__ r3W1, const float* __restrict__ r3b1,
    const float* __restrict__ r3W2, const float* __restrict__ r3b2,
    float2* __restrict__ out)         // [B][T] -> (x0,x1) f32
{
  const int lane = threadIdx.x;
  const int j = lane & 31;
  const bool hi = lane >= 32;      // high half = r2 net / z4 duties
  const int b = blockIdx.x;
  const int xaddr = ((lane ^ 32) << 2);   // ds_bpermute partner address

  auto xchg = [&](float v) -> float {
    return __int_as_float(__builtin_amdgcn_ds_bpermute(xaddr, __float_as_int(v)));
  };

  // ---- per-half net weights (column j), tanh prescale KE folded in ----
  const float* W0p = hi ? r2W0 : r1W0;
  const float* B0p = hi ? r2b0 : r1b0;
  const float* W1p = hi ? r2W1 : r1W1;
  const float* B1p = hi ? r2b1 : r1b1;
  const float* W2p = hi ? r2W2 : r1W2;
  const float sc = hi ? 0.2f : 0.3f;
  float w0K = W0p[j] * KE, b0K = B0p[j] * KE;
  float b1K = B1p[j] * KE;
  float w2sc = W2p[j] * sc;

  v2f W1v[16];
#pragma unroll
  for (int k = 0; k < 16; ++k)
    W1v[k] = mk2(W1p[(2 * k) * 32 + j] * KE, W1p[(2 * k + 1) * 32 + j] * KE);

  v2f W0Cv[12];
#pragma unroll
  for (int m = 0; m < 12; ++m)
    W0Cv[m] = mk2(r3W0[(2 * m) * 32 + j] * KE, r3W0[(2 * m + 1) * 32 + j] * KE);
  const int kbase = hi ? 16 : 0;
  v2f W1Cv[8];
#pragma unroll
  for (int k = 0; k < 8; ++k)
    W1Cv[k] = mk2(r3W1[(kbase + 2 * k) * 32 + j] * KE,
                  r3W1[(kbase + 2 * k + 1) * 32 + j] * KE);
  float b0CK = r3b0[j] * KE, b1CK = r3b1[j] * KE;
  float w2C02 = r3W2[j] * 0.2f;

  // wave-uniform scalars (biases folded with output scales)
  const float b2sA = r1b2[0] * 0.3f;
  const float b2sB = r2b2[0] * 0.2f;
  const float b2Cs = r3b2[0] * 0.2f - 0.05f;   // folds -F/V*0.5 of dCb

  __shared__ __align__(16) float zs[24];      // z state
  __shared__ __align__(16) float zb[16];      // z4 prefix [xpseq[2:], x]
  __shared__ __align__(16) float h12[2][32];  // [net][neuron] broadcast
  __shared__ __align__(16) float hR3[3][32];  // [eval: z,z23,z4][neuron]

  float x0 = xz0[b * 26 + 0];
  float x1 = xz0[b * 26 + 1];
  if (!hi && j < 24) zs[j] = xz0[b * 26 + 2 + j];
  CFENCE();

  // RK stage: low half evaluates r1(sx), high half r2(sy); readlane both.
  auto stage = [&](float sxv, float syv, float rc_m05, float CafF,
                   float& kx, float& ky) {
    float sv = hi ? syv : sxv;
    float h = tanh_pre(fmaf(sv, w0K, b0K));
    CFENCE();                      // order write after previous readers
    h12[hi][j] = h;
    CFENCE();                      // order reads after the write
    float a = dot32(&h12[hi][0], W1v, b1K);
    float v = halves_total(tanh_pre(a) * w2sc);
    float ra = rlane(v, 31) + b2sA;       // r1 (uniform)
    float rb = rlane(v, 63) + b2sB;       // r2 (uniform)
    float dCa = fmaf(-0.03f, sxv, CafF) - ra;
    float dCb = fmaf(-0.02f, syv, fmaf(-3.0f, rb, ra) + rc_m05);
    kx = dCa * (1.0f / 0.3f);
    ky = dCb * (1.0f / 0.2f);
  };

  float u = useq[b * TT];

  for (int t = 0; t < TT; ++t) {
    int tn = (t < TT - 1) ? (t + 1) : t;
    float u_nxt = useq[b * TT + tn];   // prefetch, consumed next iter
    float CafF = fmaf(u, 0.05f, 0.05f);

    if (lane == 0) out[b * TT + t] = make_float2(x0, x1);

    // z4 prefix into zb
    CFENCE();
    if (!hi && j < 16) {
      zb[j] = (j < 14) ? zs[j + 2] : ((j == 14) ? x0 : x1);
    }
    CFENCE();

    // ---- r3 x3: low computes A(z), high computes A(z4); pre-scaled ----
    const float4* zp = (const float4*)(hi ? &zb[0] : &zs[0]);
    float4 z0 = zp[0], z1 = zp[1], z2 = zp[2], z3 = zp[3];
    const float4* up = (const float4*)&zs[16];     // shared upseq tail
    float4 u0 = up[0], u1 = up[1];
    v2f aa = mk2(b0CK, 0.f), ab = mk2(0.f, 0.f);
    aa = pkfma(mk2(z0.x, z0.y), W0Cv[0], aa);
    ab = pkfma(mk2(z0.z, z0.w), W0Cv[1], ab);
    aa = pkfma(mk2(z1.x, z1.y), W0Cv[2], aa);
    ab = pkfma(mk2(z1.z, z1.w), W0Cv[3], ab);
    aa = pkfma(mk2(z2.x, z2.y), W0Cv[4], aa);
    ab = pkfma(mk2(z2.z, z2.w), W0Cv[5], ab);
    aa = pkfma(mk2(z3.x, z3.y), W0Cv[6], aa);
    ab = pkfma(mk2(z3.z, z3.w), W0Cv[7], ab);
    aa = pkfma(mk2(u0.x, u0.y), W0Cv[8], aa);
    ab = pkfma(mk2(u0.z, u0.w), W0Cv[9], ab);
    aa = pkfma(mk2(u1.x, u1.y), W0Cv[10], aa);
    ab = pkfma(mk2(u1.z, u1.w), W0Cv[11], ab);
    v2f as = aa + ab;
    float A = as.x + as.y;
    float Ap = xchg(A);                    // partner's A
    float tA = tanh_pre(A);
    CFENCE();
    if (!hi) {
      hR3[0][j] = tA;                              // h(z)
      hR3[1][j] = tanh_pre(0.5f * (A + Ap));       // h(z23), exact linearity
    } else {
      hR3[2][j] = tA;                              // h(z4)
    }
    CFENCE();
    float p0 = pdot16(&hR3[0][kbase], W1Cv);
    float p1 = pdot16(&hR3[1][kbase], W1Cv);
    float p2 = pdot16(&hR3[2][kbase], W1Cv);
    float o0 = p0 + xchg(p0) + b1CK;       // full sums, same in both halves
    float o1 = p1 + xchg(p1) + b1CK;
    float o2 = p2 + xchg(p2) + b1CK;
    float v0 = halves_total(tanh_pre(o0) * w2C02);
    float v1 = halves_total(tanh_pre(o1) * w2C02);
    float v2 = halves_total(tanh_pre(o2) * w2C02);
    float rc1  = rlane(v0, 31) + b2Cs;     // = rc - 0.05 (uniform)
    float rc23 = rlane(v1, 31) + b2Cs;
    float rc4  = rlane(v2, 31) + b2Cs;

    // ---- RK stages ----
    float kx1, ky1, kx2, ky2, kx3, ky3, kx4, ky4;
    stage(x0, x1, rc1, CafF, kx1, ky1);
    stage(fmaf(kx1, 0.5f, x0), fmaf(ky1, 0.5f, x1), rc23, CafF, kx2, ky2);
    stage(fmaf(kx2, 0.5f, x0), fmaf(ky2, 0.5f, x1), rc23, CafF, kx3, ky3);
    stage(x0 + kx3, x1 + ky3, rc4, CafF, kx4, ky4);

    // ---- state update: zplus = [xpseq[2:], x, upseq[1:], u] ----
    float znew = 0.0f;
    bool updz = (!hi) && (j < 24);
    if (updz) znew = (j < 16) ? zb[j] : ((j < 23) ? zs[j + 1] : u);
    CFENCE();                      // all reads of zs/zb complete
    if (updz) zs[j] = znew;
    x0 += (kx1 + 2.0f * (kx2 + kx3) + kx4) * (1.0f / 6.0f);
    x1 += (ky1 + 2.0f * (ky2 + ky3) + ky4) * (1.0f / 6.0f);
    u = u_nxt;
    CFENCE();                      // zs writes ordered before next-iter reads
  }
}

extern "C" void kernel_launch(void* const* d_in, const int* in_sizes, int n_in,
                              void* d_out, int out_size, void* d_ws, size_t ws_size,
                              hipStream_t stream) {
  const float* p[20];
  for (int i = 0; i < 20; ++i) p[i] = (const float*)d_in[i];
  reac_kernel<<<dim3(4096), dim3(64), 0, stream>>>(
      p[0], p[1], p[2], p[3], p[4], p[5], p[6], p[7], p[8], p[9], p[10],
      p[11], p[12], p[13], p[14], p[15], p[16], p[17], p[18], p[19],
      (float2*)d_out);
}